// Round 9
// baseline (273.648 us; speedup 1.0000x reference)
//
#include <hip/hip_runtime.h>

#define TT 512
#define LOG2E 1.44269504088896340736f

typedef float f2 __attribute__((ext_vector_type(2)));

// ---- DPP helpers (rows of 16 lanes) ----
template <int N>
__device__ __forceinline__ int rorki_(int v) {           // row_ror:N, depth-1 fan-out
    return __builtin_amdgcn_update_dpp(v, v, 0x120 + N, 0xf, 0xf, true);
}
template <int N>
__device__ __forceinline__ float rorkf_(float v) { return __int_as_float(rorki_<N>(__float_as_int(v))); }
template <int C>
__device__ __forceinline__ float shrf_(float v) {        // row_shr:N, shifted-in -> 0
    return __int_as_float(__builtin_amdgcn_update_dpp(0, __float_as_int(v), C, 0xf, 0xf, true));
}
__device__ __forceinline__ float sgm_(float v) {         // sigmoid, arg pre-scaled by log2e
    return __builtin_amdgcn_rcpf(1.f + __builtin_amdgcn_exp2f(-v));
}
__device__ __forceinline__ f2 pfma_(f2 a, f2 b, f2 c) {  // v_pk_fma_f32
    return __builtin_elementwise_fma(a, b, c);
}

__launch_bounds__(64)
__attribute__((amdgpu_waves_per_eu(2)))      // 2 waves/SIMD: budget 256 VGPR
__global__ void gru_pk(const float* __restrict__ x,
                       const float* __restrict__ W1, const float* __restrict__ Ur1,
                       const float* __restrict__ b1,
                       const float* __restrict__ W2, const float* __restrict__ Ur2,
                       const float* __restrict__ b2,
                       const float* __restrict__ Wd, const float* __restrict__ bd,
                       const float* __restrict__ Wo, const float* __restrict__ bo,
                       float* __restrict__ out)
{
    const int lane = threadIdx.x & 63;
    const int g    = (lane >> 4) & 1;   // 2 rows/wave; lanes 32-63 mirror 0-31
    const int j    = lane & 15;         // GRU2 / dense unit
    const int u1   = j & 7;             // GRU1 unit (pair-duplicated)
    const int hi   = j >> 3;            // 0: z-side, 1: r-side of the GRU1 pair
    const int gcol = u1 + 8 * hi;
    const int row  = blockIdx.x * 2 + g;
    const bool ishi = (hi != 0);
    const bool isw  = (j == 15) && (lane < 32);   // one store per row

    const float* xbase = x + (size_t)blockIdx.x * 2 * TT * 8;
    const int    xoff  = g * TT * 8 + u1;
    float* outrow = out + (size_t)row * TT;

    // ---- trace the DIRECT ror:k permutation (layout-proof weight order) ----
    int Lk[16];
    Lk[0]  = j;
    Lk[1]  = rorki_<1>(j);   Lk[2]  = rorki_<2>(j);   Lk[3]  = rorki_<3>(j);
    Lk[4]  = rorki_<4>(j);   Lk[5]  = rorki_<5>(j);   Lk[6]  = rorki_<6>(j);
    Lk[7]  = rorki_<7>(j);   Lk[8]  = rorki_<8>(j);   Lk[9]  = rorki_<9>(j);
    Lk[10] = rorki_<10>(j);  Lk[11] = rorki_<11>(j);  Lk[12] = rorki_<12>(j);
    Lk[13] = rorki_<13>(j);  Lk[14] = rorki_<14>(j);  Lk[15] = rorki_<15>(j);

    // ---- packed weights: tap-pair (2k, 2k+1) per f2 ----
    f2 Pz[8], Pr[8], Ph[8], Pd[8];                 // h2 fan (16 taps)
#pragma unroll
    for (int k = 0; k < 8; ++k) {
        const int a = Lk[2 * k], b = Lk[2 * k + 1];
        Pz[k] = f2{LOG2E * Ur2[a * 48 + j],      LOG2E * Ur2[b * 48 + j]};
        Pr[k] = f2{LOG2E * Ur2[a * 48 + 16 + j], LOG2E * Ur2[b * 48 + 16 + j]};
        Ph[k] = f2{Ur2[a * 48 + 32 + j],         Ur2[b * 48 + 32 + j]};
        Pd[k] = f2{Wd[a * 16 + j],               Wd[b * 16 + j]};
    }
    f2 Vz[4], Vr[4], Vh[4], VC[4], VQ[4];          // h1 fan (8 taps)
    f2 Gx[4], Hx[4];                               // x fan (8 taps)
#pragma unroll
    for (int k = 0; k < 4; ++k) {
        const int a = Lk[2 * k] & 7, b = Lk[2 * k + 1] & 7;
        Vz[k] = f2{LOG2E * W2[a * 48 + j],       LOG2E * W2[b * 48 + j]};
        Vr[k] = f2{LOG2E * W2[a * 48 + 16 + j],  LOG2E * W2[b * 48 + 16 + j]};
        Vh[k] = f2{W2[a * 48 + 32 + j],          W2[b * 48 + 32 + j]};
        VC[k] = f2{LOG2E * Ur1[a * 24 + gcol],   LOG2E * Ur1[b * 24 + gcol]};
        VQ[k] = f2{Ur1[a * 24 + 16 + u1],        Ur1[b * 24 + 16 + u1]};
        Gx[k] = f2{LOG2E * W1[a * 24 + gcol],    LOG2E * W1[b * 24 + gcol]};
        Hx[k] = f2{W1[a * 24 + 16 + u1],         W1[b * 24 + 16 + u1]};
    }
    const float bAzr = LOG2E * (b1[gcol] + b1[24 + gcol]);
    const float bGh  = b1[16 + u1];
    const float bIh  = b1[40 + u1];
    const float bA2  = LOG2E * (b2[j] + b2[48 + j]);
    const float bB2  = LOG2E * (b2[16 + j] + b2[64 + j]);
    const float bC2  = b2[80 + j];
    const float bD2  = b2[32 + j];
    const float bdj  = bd[j], woj = Wo[j], boo = bo[0];

    float h1own = 0.f, h2own = 0.f;
    float azrP = bAzr, ihP = bIh;                  // carried GRU1 h-side partials

    float xA = xbase[0 * 8 + xoff];
    float xB = xbase[1 * 8 + xoff];
    float xC = xbase[2 * 8 + xoff];

#define GSTEP(SS, XCUR, XFILL)                                                   \
    {                                                                            \
        const int s = (SS);                                                      \
        /* h2 fan-out: 15 depth-1 DPPs, packed into 8 tap-pairs */               \
        const float h0 = h2own;                                                  \
        f2 tp[8];                                                                \
        tp[0] = f2{h0,             rorkf_<1>(h0)};                               \
        tp[1] = f2{rorkf_<2>(h0),  rorkf_<3>(h0)};                               \
        tp[2] = f2{rorkf_<4>(h0),  rorkf_<5>(h0)};                               \
        tp[3] = f2{rorkf_<6>(h0),  rorkf_<7>(h0)};                               \
        tp[4] = f2{rorkf_<8>(h0),  rorkf_<9>(h0)};                               \
        tp[5] = f2{rorkf_<10>(h0), rorkf_<11>(h0)};                              \
        tp[6] = f2{rorkf_<12>(h0), rorkf_<13>(h0)};                              \
        tp[7] = f2{rorkf_<14>(h0), rorkf_<15>(h0)};                              \
        f2 za = f2{bA2, 0.f}, ra = f2{bB2, 0.f};                                 \
        f2 ha = f2{bC2, 0.f}, da = f2{bdj, 0.f};                                 \
        _Pragma("unroll")                                                        \
        for (int k = 0; k < 8; ++k) {                                            \
            za = pfma_(tp[k], Pz[k], za);  ra = pfma_(tp[k], Pr[k], ra);         \
            ha = pfma_(tp[k], Ph[k], ha);  da = pfma_(tp[k], Pd[k], da);         \
        }                                                                        \
        /* x fan-out: 7 depth-1 DPPs, 4 tap-pairs */                             \
        const float x0 = XCUR;                                                   \
        f2 xp[4];                                                                \
        xp[0] = f2{x0,            rorkf_<1>(x0)};                                \
        xp[1] = f2{rorkf_<2>(x0), rorkf_<3>(x0)};                                \
        xp[2] = f2{rorkf_<4>(x0), rorkf_<5>(x0)};                                \
        xp[3] = f2{rorkf_<6>(x0), rorkf_<7>(x0)};                                \
        f2 axp = f2{azrP, 0.f}, ghp = f2{bGh, 0.f};                              \
        _Pragma("unroll")                                                        \
        for (int k = 0; k < 4; ++k) {                                            \
            axp = pfma_(xp[k], Gx[k], axp);  ghp = pfma_(xp[k], Hx[k], ghp);     \
        }                                                                        \
        XFILL = xbase[((s + 3) & (TT - 1)) * 8 + xoff];  /* prefetch s+3 */      \
        /* GRU1: one sigmoid; partner's sigmoid via ror8 of the result */        \
        const float azrC = axp.x + axp.y;                                        \
        const float s_own = sgm_(azrC);                                          \
        const float s_sw  = rorkf_<8>(s_own);                                    \
        const float z1 = ishi ? s_sw : s_own;                                    \
        const float r1 = ishi ? s_own : s_sw;                                    \
        const float ghxC = ghp.x + ghp.y;                                        \
        const float hh1 = fmaxf(fmaf(r1, ihP, ghxC), 0.f);                       \
        h1own = fmaf(z1, h1own - hh1, hh1);                                      \
        /* h1 fan-out: W2 taps + next-step GRU1 h-taps, 4 tap-pairs */           \
        const float n0 = h1own;                                                  \
        f2 np[4];                                                                \
        np[0] = f2{n0,            rorkf_<1>(n0)};                                \
        np[1] = f2{rorkf_<2>(n0), rorkf_<3>(n0)};                                \
        np[2] = f2{rorkf_<4>(n0), rorkf_<5>(n0)};                                \
        np[3] = f2{rorkf_<6>(n0), rorkf_<7>(n0)};                                \
        f2 hbp = f2{bD2, 0.f}, aNp = f2{bAzr, 0.f}, iNp = f2{bIh, 0.f};          \
        _Pragma("unroll")                                                        \
        for (int k = 0; k < 4; ++k) {                                            \
            za  = pfma_(np[k], Vz[k], za);   ra  = pfma_(np[k], Vr[k], ra);      \
            hbp = pfma_(np[k], Vh[k], hbp);                                      \
            aNp = pfma_(np[k], VC[k], aNp);  iNp = pfma_(np[k], VQ[k], iNp);     \
        }                                                                        \
        azrP = aNp.x + aNp.y;  ihP = iNp.x + iNp.y;                              \
        /* GRU2 nonlinearity + state */                                          \
        const float zaC = za.x + za.y, raC = ra.x + ra.y;                        \
        const float haC = ha.x + ha.y, hbC = hbp.x + hbp.y;                      \
        const float z2 = sgm_(zaC), r2 = sgm_(raC);                              \
        const float hh2 = fmaxf(fmaf(r2, haC, hbC), 0.f);                        \
        h2own = fmaf(z2, h2own - hh2, hh2);                                      \
        /* dense for step s-1 (da used h2(s-1)) */                               \
        float e = fmaxf(da.x + da.y, 0.f) * woj;                                 \
        e += shrf_<0x118>(e);                                                    \
        e += shrf_<0x114>(e);                                                    \
        e += shrf_<0x112>(e);                                                    \
        e += shrf_<0x111>(e);                                                    \
        if (s > 0) { if (isw) outrow[s - 1] = e + boo; }                         \
    }

    for (int s0 = 0; s0 < TT; s0 += 4) {
        GSTEP(s0 + 0, xA, xA)
        GSTEP(s0 + 1, xB, xB)
        GSTEP(s0 + 2, xC, xC)
        GSTEP(s0 + 3, xA, xA)
        { float t = xB; xB = xC; xC = xA; xA = t; }
    }
#undef GSTEP

    // epilogue: dense for s = 511 from final h2
    {
        const float h0 = h2own;
        f2 tp[8];
        tp[0] = f2{h0,             rorkf_<1>(h0)};
        tp[1] = f2{rorkf_<2>(h0),  rorkf_<3>(h0)};
        tp[2] = f2{rorkf_<4>(h0),  rorkf_<5>(h0)};
        tp[3] = f2{rorkf_<6>(h0),  rorkf_<7>(h0)};
        tp[4] = f2{rorkf_<8>(h0),  rorkf_<9>(h0)};
        tp[5] = f2{rorkf_<10>(h0), rorkf_<11>(h0)};
        tp[6] = f2{rorkf_<12>(h0), rorkf_<13>(h0)};
        tp[7] = f2{rorkf_<14>(h0), rorkf_<15>(h0)};
        f2 da = f2{bdj, 0.f};
#pragma unroll
        for (int k = 0; k < 8; ++k) da = pfma_(tp[k], Pd[k], da);
        float e = fmaxf(da.x + da.y, 0.f) * woj;
        e += shrf_<0x118>(e);
        e += shrf_<0x114>(e);
        e += shrf_<0x112>(e);
        e += shrf_<0x111>(e);
        if (isw) outrow[TT - 1] = e + boo;
    }
}

extern "C" void kernel_launch(void* const* d_in, const int* in_sizes, int n_in,
                              void* d_out, int out_size, void* d_ws, size_t ws_size,
                              hipStream_t stream) {
    const float* x   = (const float*)d_in[0];
    const float* W1  = (const float*)d_in[1];
    const float* Ur1 = (const float*)d_in[2];
    const float* b1  = (const float*)d_in[3];
    const float* W2  = (const float*)d_in[4];
    const float* Ur2 = (const float*)d_in[5];
    const float* b2  = (const float*)d_in[6];
    const float* Wd  = (const float*)d_in[7];
    const float* bd  = (const float*)d_in[8];
    const float* Wo  = (const float*)d_in[9];
    const float* bo  = (const float*)d_in[10];
    float* out = (float*)d_out;

    dim3 grid(4096 / 2);   // 2048 blocks x 1 wave = 2 waves/SIMD
    dim3 block(64);        // 2 rows x 16 lanes (lanes 32-63 mirror), zero LDS
    gru_pk<<<grid, block, 0, stream>>>(x, W1, Ur1, b1, W2, Ur2, b2,
                                       Wd, bd, Wo, bo, out);
}